// Round 13
// baseline (6944.575 us; speedup 1.0000x reference)
//
#include <hip/hip_runtime.h>
#include <hip/hip_cooperative_groups.h>
#include <cstddef>
#include <cstdint>

namespace cg = cooperative_groups;

using f32x4  = __attribute__((ext_vector_type(4))) float;
using bf16x8 = __attribute__((ext_vector_type(8))) short;
using u16x4  = __attribute__((ext_vector_type(4))) unsigned short;
typedef unsigned short u16;

#define LMDA 0.005f

__device__ __forceinline__ u16 f2bf(float f) {
    union { float f; uint32_t u; } v; v.f = f;
    return (u16)((v.u + 0x7FFFu + ((v.u >> 16) & 1u)) >> 16);
}
__device__ __forceinline__ float bf2f(u16 b) {
    union { uint32_t u; float f; } v; v.u = ((uint32_t)b) << 16;
    return v.f;
}
__device__ __forceinline__ void split2(float x, u16& h, u16& l) {
    h = f2bf(x); l = f2bf(x - bf2f(h));
}
__device__ __forceinline__ float sthr(float x) {
    float ax = fabsf(x) - LMDA;
    return ax > 0.0f ? copysignf(ax, x) : 0.0f;
}

// async 16B global -> LDS (HW writes lane l at ldsbase + l*16)
__device__ __forceinline__ void gload16(const u16* g, u16* l) {
    __builtin_amdgcn_global_load_lds(
        (const __attribute__((address_space(1))) unsigned int*)(const void*)g,
        (__attribute__((address_space(3))) unsigned int*)(void*)l, 16, 0, 0);
}

// ---------------------------------------------------------------------------
// COOPERATIVE PERSISTENT ISTA KERNEL: all 149 iterations in one launch.
//   R@W = 0.8*R + Rh@Wo   (Wo = -0.2*offdiag(U@U^T), single bf16, 2 MB)
// Geometry identical to r12's passing gemm_one<1,0>: tile 64m x 128n, grid
// 256 (32tr x 8tc), 512 thr = 8 waves (2mr x 4nc), wavetile 32x32 = 2x2 frags
// of 16x16x32, BK=64 -> 16 k-steps, LDS dbuf 2 x 24 x 1KB fragment-ordered
// chunks (lane*16B = linear global_load_lds dest, conflict-free ds_read_b128).
// Per-iteration: [Wo-chunk prefetch of step 0] -> grid.sync() -> R-chunk
// stage of step 0 -> 16-step pipelined k-sweep -> fused epilogue
// R' = split(st(acc + 0.8*(Rh+Rl) + cs_regs)) -> buffer swap.
// Csc tile lives in 16 VGPRs for the whole kernel (8 MB/iter traffic saved).
// One grid.sync per iteration is sufficient: buffer X is read in iter t
// (k-sweep) and written in iter t+1 (epilogue), separated by the sync.
// ---------------------------------------------------------------------------
__global__ __launch_bounds__(512, 2)
void pc_coop(const u16* __restrict__ Rah, const u16* __restrict__ Ral,
             u16* __restrict__ Rbh, u16* __restrict__ Rbl,
             const u16* __restrict__ Woh, const float* __restrict__ Csc)
{
    __shared__ __align__(16) u16 S[2][24 * 512];   // 2 x 24 KiB

    cg::grid_group grid = cg::this_grid();

    // XCD-aware bijective swizzle (256 % 8 == 0)
    const int fid = blockIdx.x;
    const int sid = (fid & 7) * 32 + (fid >> 3);
    const int tr = sid >> 3;              // 0..31
    const int tc = sid & 7;               // 0..7
    const int row0 = tr << 6;             // R rows [row0, +64)
    const int col0 = tc << 7;             // n cols [col0, +128)

    const int tid  = threadIdx.x;
    const int lane = tid & 63;
    const int w    = tid >> 6;            // 0..7
    const int mr   = w >> 2;              // 0..1 (m-half)
    const int nc   = w & 3;               // 0..3 (n-quarter)
    const int l15  = lane & 15;
    const int lg   = lane >> 4;           // 0..3
    const int l8   = lane << 3;           // u16 offset of lane's 16B

    // ---- staging table: 24 chunks of 1KB per step (8 Rh + 16 Wo), 3/thread
    // A chunk c in [0,8):  kh=(c>>2)&1, g=c&3 : Rh rows row0+g*16
    // B chunk c in [8,24): cb=c-8, kh=cb>>3, g=cb&7 : Woh rows col0+g*16
    bool      isA[3];
    size_t    aoff[3];
    const u16* bptr[3];
    int       loff[3];
    #pragma unroll
    for (int t = 0; t < 3; ++t) {
        const int c = w * 3 + t;
        if (c < 8) {
            const int kh = (c >> 2) & 1;
            const int r  = row0 + ((c & 3) << 4) + l15;
            isA[t]  = true;
            aoff[t] = ((size_t)r << 10) + (kh << 5) + (lg << 3);
            bptr[t] = nullptr;
        } else {
            const int cb = c - 8;
            const int kh = cb >> 3;
            const int r  = col0 + ((cb & 7) << 4) + l15;
            isA[t]  = false;
            aoff[t] = 0;
            bptr[t] = Woh + ((size_t)r << 10) + (kh << 5) + (lg << 3);
        }
        loff[t] = (c << 9) + l8;
    }
    auto stageB = [&](int b, int k) {
        #pragma unroll
        for (int t = 0; t < 3; ++t)
            if (!isA[t]) gload16(bptr[t] + k, &S[b][loff[t]]);
    };
    auto stageA = [&](int b, int k, const u16* curh) {
        #pragma unroll
        for (int t = 0; t < 3; ++t)
            if (isA[t]) gload16(curh + aoff[t] + k, &S[b][loff[t]]);
    };
    auto stageAll = [&](int b, int k, const u16* curh) {
        #pragma unroll
        for (int t = 0; t < 3; ++t)
            gload16(isA[t] ? curh + aoff[t] + k : bptr[t] + k, &S[b][loff[t]]);
    };

    // ---- epilogue indices + Csc tile in registers (iteration-invariant) ----
    size_t eidx[2][2];
    f32x4  cs[2][2];
    #pragma unroll
    for (int mf = 0; mf < 2; ++mf)
        #pragma unroll
        for (int nf = 0; nf < 2; ++nf) {
            const int m  = row0 + (mr << 5) + (mf << 4) + l15;
            const int n0 = col0 + (nc << 5) + (nf << 4) + (lg << 2);
            eidx[mf][nf] = ((size_t)m << 10) + n0;
            cs[mf][nf]   = *(const f32x4*)&Csc[eidx[mf][nf]];
        }

    const u16* curh = Rah; const u16* curl = Ral;
    u16* nxth = Rbh;       u16* nxtl = Rbl;

    for (int it = 0; it < 149; ++it) {
        // Wo chunks of step 0 are R-independent: issue before the sync.
        stageB(0, 0);
        if (it > 0) grid.sync();
        stageA(0, 0, curh);

        f32x4 acc[2][2] = {};

        for (int s = 0; s < 16; ++s) {
            asm volatile("s_waitcnt vmcnt(0)" ::: "memory");
            __builtin_amdgcn_s_barrier();
            asm volatile("" ::: "memory");
            if (s < 15) stageAll((s + 1) & 1, (s + 1) << 6, curh);

            const u16* Sb = S[s & 1];
            bf16x8 rh[2][2], wo[2][2];
            #pragma unroll
            for (int kh = 0; kh < 2; ++kh) {
                #pragma unroll
                for (int mf = 0; mf < 2; ++mf) {
                    const int g = (mr << 1) + mf;
                    rh[mf][kh] = *(const bf16x8*)&Sb[(((kh << 2) + g) << 9) + l8];
                }
                #pragma unroll
                for (int nf = 0; nf < 2; ++nf) {
                    const int g = (nc << 1) + nf;
                    wo[nf][kh] = *(const bf16x8*)&Sb[((8 + (kh << 3) + g) << 9) + l8];
                }
            }
            #pragma unroll
            for (int kh = 0; kh < 2; ++kh)
                #pragma unroll
                for (int mf = 0; mf < 2; ++mf)
                    #pragma unroll
                    for (int nf = 0; nf < 2; ++nf)
                        acc[mf][nf] = __builtin_amdgcn_mfma_f32_16x16x32_bf16(
                            wo[nf][kh], rh[mf][kh], acc[mf][nf], 0, 0, 0);
            asm volatile("" ::: "memory");
        }

        // ---- fused epilogue ----
        #pragma unroll
        for (int mf = 0; mf < 2; ++mf) {
            #pragma unroll
            for (int nf = 0; nf < 2; ++nf) {
                const size_t idx = eidx[mf][nf];
                const u16x4 rh4 = *(const u16x4*)&curh[idx];
                const u16x4 rl4 = *(const u16x4*)&curl[idx];
                u16x4 hv, lv;
                #pragma unroll
                for (int e = 0; e < 4; ++e) {
                    float r = bf2f(rh4[e]) + bf2f(rl4[e]);
                    float x = acc[mf][nf][e] + 0.8f * r + cs[mf][nf][e];
                    u16 hh, ll; split2(sthr(x), hh, ll);
                    hv[e] = hh; lv[e] = ll;
                }
                *(u16x4*)&nxth[idx] = hv;
                *(u16x4*)&nxtl[idx] = lv;
            }
        }

        // swap buffers
        const u16* th = curh; const u16* tl = curl;
        curh = nxth; curl = nxtl;
        nxth = (u16*)th; nxtl = (u16*)tl;
    }
}

// ---------------------------------------------------------------------------
// PER-LAUNCH ITERATION KERNEL (r12, passing) — final out + runtime fallback.
// NPROD=1: acc = Rh@Bm ; NPROD=2: acc = (Rh+Rl)@Bm
// OM 0: R' = split(st(acc + 0.8(Rh+Rl) + Cs)) ; OM 1: OutF = acc
// ---------------------------------------------------------------------------
template<int NPROD, int OM>
__global__ __launch_bounds__(512, 2)
void gemm_one(const u16* __restrict__ Rh, const u16* __restrict__ Rl,
              const u16* __restrict__ Bm,
              const float* __restrict__ Cs,
              u16* __restrict__ Nh, u16* __restrict__ Nl,
              float* __restrict__ OutF)
{
    constexpr int NCH = 8 * NPROD + 16;
    constexpr int CPW = NCH / 8;
    __shared__ __align__(16) u16 S[2][NCH * 512];

    const int fid = blockIdx.x;
    const int sid = (fid & 7) * 32 + (fid >> 3);
    const int tr = sid >> 3;
    const int tc = sid & 7;
    const int row0 = tr << 6;
    const int col0 = tc << 7;

    const int tid  = threadIdx.x;
    const int lane = tid & 63;
    const int w    = tid >> 6;
    const int mr   = w >> 2;
    const int nc   = w & 3;
    const int l15  = lane & 15;
    const int lg   = lane >> 4;
    const int l8   = lane << 3;

    const u16* gsrc[CPW];
    int loff[CPW];
    #pragma unroll
    for (int t = 0; t < CPW; ++t) {
        const int c = w * CPW + t;
        const u16* base;
        int r, kh;
        if (c < 8 * NPROD) {
            const int h = c >> 3;
            kh = (c >> 2) & 1;
            base = h ? Rl : Rh;
            r = row0 + ((c & 3) << 4) + l15;
        } else {
            const int cb = c - 8 * NPROD;
            kh = cb >> 3;
            base = Bm;
            r = col0 + ((cb & 7) << 4) + l15;
        }
        gsrc[t] = base + ((size_t)r << 10) + (kh << 5) + (lg << 3);
        loff[t] = (c << 9) + l8;
    }
    auto stage = [&](int b, int k) {
        #pragma unroll
        for (int t = 0; t < CPW; ++t)
            gload16(gsrc[t] + k, &S[b][loff[t]]);
    };

    f32x4 acc[2][2] = {};

    stage(0, 0);

    for (int s = 0; s < 16; ++s) {
        asm volatile("s_waitcnt vmcnt(0)" ::: "memory");
        __builtin_amdgcn_s_barrier();
        asm volatile("" ::: "memory");
        if (s < 15) stage((s + 1) & 1, (s + 1) << 6);

        const u16* Sb = S[s & 1];
        bf16x8 rh[2][2], rl[2][2], wo[2][2];
        #pragma unroll
        for (int kh = 0; kh < 2; ++kh) {
            #pragma unroll
            for (int mf = 0; mf < 2; ++mf) {
                const int g = (mr << 1) + mf;
                rh[mf][kh] = *(const bf16x8*)&Sb[(((kh << 2) + g) << 9) + l8];
                if (NPROD == 2)
                    rl[mf][kh] = *(const bf16x8*)&Sb[((8 + (kh << 2) + g) << 9) + l8];
            }
            #pragma unroll
            for (int nf = 0; nf < 2; ++nf) {
                const int g = (nc << 1) + nf;
                wo[nf][kh] = *(const bf16x8*)&Sb[((8 * NPROD + (kh << 3) + g) << 9) + l8];
            }
        }
        #pragma unroll
        for (int kh = 0; kh < 2; ++kh)
            #pragma unroll
            for (int mf = 0; mf < 2; ++mf)
                #pragma unroll
                for (int nf = 0; nf < 2; ++nf) {
                    acc[mf][nf] = __builtin_amdgcn_mfma_f32_16x16x32_bf16(
                        wo[nf][kh], rh[mf][kh], acc[mf][nf], 0, 0, 0);
                    if (NPROD == 2)
                        acc[mf][nf] = __builtin_amdgcn_mfma_f32_16x16x32_bf16(
                            wo[nf][kh], rl[mf][kh], acc[mf][nf], 0, 0, 0);
                }
        asm volatile("" ::: "memory");
    }

    #pragma unroll
    for (int mf = 0; mf < 2; ++mf) {
        #pragma unroll
        for (int nf = 0; nf < 2; ++nf) {
            const int m  = row0 + (mr << 5) + (mf << 4) + l15;
            const int n0 = col0 + (nc << 5) + (nf << 4) + (lg << 2);
            const size_t idx = ((size_t)m << 10) + n0;
            if (OM == 0) {
                const u16x4 rh4 = *(const u16x4*)&Rh[idx];
                const u16x4 rl4 = *(const u16x4*)&Rl[idx];
                const f32x4 csv = *(const f32x4*)&Cs[idx];
                u16x4 hv, lv;
                #pragma unroll
                for (int e = 0; e < 4; ++e) {
                    float r  = bf2f(rh4[e]) + bf2f(rl4[e]);
                    float x  = acc[mf][nf][e] + 0.8f * r + csv[e];
                    u16 hh, ll; split2(sthr(x), hh, ll);
                    hv[e] = hh; lv[e] = ll;
                }
                *(u16x4*)&Nh[idx] = hv;
                *(u16x4*)&Nl[idx] = lv;
            } else {
                *(f32x4*)&OutF[idx] = acc[mf][nf];
            }
        }
    }
}

// ---------------------------------------------------------------------------
// PROLOGUE GEMM (round-5 machinery, passing): fused-3 split-bf16 NT GEMM.
// EPI 1: OutF = 0.2*acc ; R = split(st(OutF))       (Csc and R1)
// EPI 4: OutH = f2bf(diag? 0 : -0.2*acc)            (Woh, single bf16)
// ---------------------------------------------------------------------------
template<int EPI>
__global__ __launch_bounds__(512, 2)
void gemm_ista(const u16* __restrict__ Ah, const u16* __restrict__ Al,
               const u16* __restrict__ Bh, const u16* __restrict__ Bl,
               int Nt,
               const float* __restrict__ Cs, float* __restrict__ OutF,
               u16* __restrict__ OutH, u16* __restrict__ OutL)
{
    __shared__ __align__(16) u16 S[3][48 * 512];   // 144 KiB

    const int nwg = gridDim.x;
    const int fid = blockIdx.x;
    const int sid = (fid & 7) * (nwg >> 3) + (fid >> 3);
    const int row0 = (sid / Nt) << 7;
    const int col0 = (sid % Nt) << 6;

    const int tid  = threadIdx.x;
    const int lane = tid & 63;
    const int w    = tid >> 6;
    const int mr = w >> 2, nc = (w >> 1) & 1, ks = w & 1;

    const u16* gb[6];
    int cf[6];
    #pragma unroll
    for (int t = 0; t < 6; ++t) {
        const int c = w * 6 + t;
        const u16* base; int r; int kss;
        if (c < 32) {
            const int h = (c >> 4) & 1; kss = (c >> 3) & 1;
            base = h ? Al : Ah;
            r = row0 + ((c & 7) << 4) + (lane & 15);
        } else {
            const int cb = c - 32;
            const int h = (cb >> 3) & 1; kss = (cb >> 2) & 1;
            base = h ? Bl : Bh;
            r = col0 + ((cb & 3) << 4) + (lane & 15);
        }
        gb[t] = base + ((size_t)r << 10) + (kss << 5) + ((lane >> 4) << 3);
        cf[t] = c << 9;
    }
    auto stage = [&](int b, int koff) {
        #pragma unroll
        for (int t = 0; t < 6; ++t)
            gload16(gb[t] + koff, &S[b][cf[t]]);
    };

    f32x4 acc[4][2] = {};

    stage(0, 0);
    stage(1, 64);

    #pragma unroll
    for (int s = 0; s < 16; ++s) {
        if (s <= 14) asm volatile("s_waitcnt vmcnt(6)" ::: "memory");
        else         asm volatile("s_waitcnt vmcnt(0)" ::: "memory");
        __builtin_amdgcn_s_barrier();
        asm volatile("" ::: "memory");
        if (s + 2 < 16) stage((s + 2) % 3, (s + 2) << 6);

        const u16* Sb = S[s % 3];
        const int ab = (ks << 3) + (mr << 2);
        const int bb = 32 + (ks << 2) + (nc << 1);
        bf16x8 ah[4], al[4], bh[2], bl[2];
        #pragma unroll
        for (int i = 0; i < 4; ++i) {
            ah[i] = *(const bf16x8*)&Sb[(ab + i)      * 512 + (lane << 3)];
            al[i] = *(const bf16x8*)&Sb[(ab + 16 + i) * 512 + (lane << 3)];
        }
        #pragma unroll
        for (int j = 0; j < 2; ++j) {
            bh[j] = *(const bf16x8*)&Sb[(bb + j)     * 512 + (lane << 3)];
            bl[j] = *(const bf16x8*)&Sb[(bb + 8 + j) * 512 + (lane << 3)];
        }
        #pragma unroll
        for (int i = 0; i < 4; ++i)
            #pragma unroll
            for (int j = 0; j < 2; ++j)
                acc[i][j] = __builtin_amdgcn_mfma_f32_16x16x32_bf16(ah[i], bh[j], acc[i][j], 0, 0, 0);
        #pragma unroll
        for (int i = 0; i < 4; ++i)
            #pragma unroll
            for (int j = 0; j < 2; ++j)
                acc[i][j] = __builtin_amdgcn_mfma_f32_16x16x32_bf16(al[i], bh[j], acc[i][j], 0, 0, 0);
        #pragma unroll
        for (int i = 0; i < 4; ++i)
            #pragma unroll
            for (int j = 0; j < 2; ++j)
                acc[i][j] = __builtin_amdgcn_mfma_f32_16x16x32_bf16(ah[i], bl[j], acc[i][j], 0, 0, 0);
        asm volatile("" ::: "memory");
    }

    __syncthreads();
    f32x4* red = (f32x4*)&S[0][0];
    const int wquad = (mr << 1) + nc;
    #pragma unroll
    for (int ih = 0; ih < 2; ++ih) {
        #pragma unroll
        for (int j = 0; j < 2; ++j) {
            const int isrc = ks ? ih : (2 + ih);
            const int slot = ((((wquad << 1) | ks) << 2) | (ih << 1) | j);
            red[slot * 64 + lane] = acc[isrc][j];
        }
    }
    __syncthreads();

    const int gr0 = row0 + (mr << 6) + ((lane >> 4) << 2);
    const int gc  = col0 + (nc << 5) + (lane & 15);
    #pragma unroll
    for (int ih = 0; ih < 2; ++ih) {
        #pragma unroll
        for (int j = 0; j < 2; ++j) {
            const int i    = ks ? (2 + ih) : ih;
            const int slot = ((((wquad << 1) | (ks ^ 1)) << 2) | (ih << 1) | j);
            f32x4 sum = acc[i][j] + red[slot * 64 + lane];
            #pragma unroll
            for (int e = 0; e < 4; ++e) {
                const int grow = gr0 + (i << 4) + e;
                const int gcol = gc + (j << 4);
                const size_t idx = ((size_t)grow << 10) + gcol;
                const float p = sum[e];
                if (EPI == 1) {
                    float f = 0.2f * p;
                    OutF[idx] = f;
                    u16 h, l; split2(sthr(f), h, l);
                    OutH[idx] = h; OutL[idx] = l;
                } else {   // EPI 4: Woh = bf16(-0.2*offdiag)
                    float x = (grow == gcol) ? 0.0f : -0.2f * p;
                    OutH[idx] = f2bf(x);
                }
            }
        }
    }
}

// fp32 -> (hi, lo) bf16 pair, elementwise
__global__ void k_split(const float* __restrict__ in, u16* __restrict__ hi,
                        u16* __restrict__ lo, int n)
{
    int i = blockIdx.x * 256 + threadIdx.x;
    if (i < n) { u16 h, l; split2(in[i], h, l); hi[i] = h; lo[i] = l; }
}

// Ut[j][k] = U[k][j] as bf16 pair
__global__ __launch_bounds__(256)
void k_transpose_split(const float* __restrict__ in, u16* __restrict__ hi,
                       u16* __restrict__ lo)
{
    __shared__ float t[32][33];
    const int bx = blockIdx.x, by = blockIdx.y;
    const int lx = threadIdx.x & 31, ly = threadIdx.x >> 5;
    #pragma unroll
    for (int rr = 0; rr < 4; ++rr) {
        int r = ly * 4 + rr;
        t[r][lx] = in[(size_t)(by * 32 + r) * 1024 + bx * 32 + lx];
    }
    __syncthreads();
    #pragma unroll
    for (int rr = 0; rr < 4; ++rr) {
        int r = ly * 4 + rr;
        u16 h, l; split2(t[lx][r], h, l);
        size_t idx = (size_t)(bx * 32 + r) * 1024 + by * 32 + lx;
        hi[idx] = h; lo[idx] = l;
    }
}

extern "C" void kernel_launch(void* const* d_in, const int* in_sizes, int n_in,
                              void* d_out, int out_size, void* d_ws, size_t ws_size,
                              hipStream_t stream) {
    const float* img = (const float*)d_in[0];   // (2048, 1024) fp32
    const float* U   = (const float*)d_in[1];   // (1024, 1024) fp32
    float* out = (float*)d_out;                 // (2048, 1024) fp32

    char* ws = (char*)d_ws;
    auto MB = [](size_t m) { return m << 20; };
    u16*   Uh  = (u16*)(ws + MB(0));
    u16*   Ul  = (u16*)(ws + MB(2));
    u16*   Uth = (u16*)(ws + MB(4));
    u16*   Utl = (u16*)(ws + MB(6));
    u16*   Woh = (u16*)(ws + MB(8));             // 2 MB single-bf16 offdiag W
    float* Csc = (float*)(ws + MB(12));          // 8 MB
    u16*   Rah = (u16*)(ws + MB(20));
    u16*   Ral = (u16*)(ws + MB(24));
    u16*   Rbh = (u16*)(ws + MB(28));
    u16*   Rbl = (u16*)(ws + MB(32));            // ends at 36 MB
    u16*   Ih  = Rbh;   // img split lives only until Csc is built
    u16*   Il  = Rbl;

    // ---- prologue ----
    k_split<<<4096, 256, 0, stream>>>(U, Uh, Ul, 1024 * 1024);
    k_split<<<8192, 256, 0, stream>>>(img, Ih, Il, 2048 * 1024);
    k_transpose_split<<<dim3(32, 32), 256, 0, stream>>>(U, Uth, Utl);

    // Woh = bf16(-0.2 * offdiag(U @ U^T))
    gemm_ista<4><<<128, 512, 0, stream>>>(Uh, Ul, Uh, Ul, 16,
                                          nullptr, nullptr, Woh, nullptr);
    // Csc = 0.2 * img @ U^T ; R1 = st(Csc)
    gemm_ista<1><<<256, 512, 0, stream>>>(Ih, Il, Uh, Ul, 16,
                                          nullptr, Csc, Rah, Ral);

    // ---- iterations 2..150 in ONE cooperative persistent kernel ----
    void* args[] = {(void*)&Rah, (void*)&Ral, (void*)&Rbh, (void*)&Rbl,
                    (void*)&Woh, (void*)&Csc};
    hipError_t cerr = hipLaunchCooperativeKernel(
        (void*)pc_coop, dim3(256), dim3(512), args, 0, stream);

    u16 *ch, *cl;
    if (cerr == hipSuccess) {
        // 149 in-kernel swaps starting from (Ra -> Rb): final R in Rb.
        ch = Rbh; cl = Rbl;
    } else {
        // fallback: r12 per-launch loop
        u16 *fch = Rah, *fcl = Ral, *nh = Rbh, *nl = Rbl;
        for (int it = 0; it < 149; ++it) {
            gemm_one<1, 0><<<256, 512, 0, stream>>>(fch, fcl, Woh, Csc,
                                                    nh, nl, nullptr);
            u16* t;
            t = fch; fch = nh; nh = t;
            t = fcl; fcl = nl; nl = t;
        }
        ch = fch; cl = fcl;
    }

    // ---- out = R @ U (2-product against Ut, one-shot) ----
    gemm_one<2, 1><<<256, 512, 0, stream>>>(ch, cl, Uth, nullptr,
                                            nullptr, nullptr, out);
}

// Round 14
// 2690.931 us; speedup vs baseline: 2.5807x; 2.5807x over previous
//
#include <hip/hip_runtime.h>
#include <cstddef>
#include <cstdint>

using f32x4  = __attribute__((ext_vector_type(4))) float;
using bf16x8 = __attribute__((ext_vector_type(8))) short;
using u16x4  = __attribute__((ext_vector_type(4))) unsigned short;
using u32x4  = __attribute__((ext_vector_type(4))) unsigned int;
typedef unsigned short u16;
typedef unsigned int   u32;

#define LMDA 0.005f

__device__ __forceinline__ u16 f2bf(float f) {
    union { float f; uint32_t u; } v; v.f = f;
    return (u16)((v.u + 0x7FFFu + ((v.u >> 16) & 1u)) >> 16);
}
__device__ __forceinline__ float bf2f(u16 b) {
    union { uint32_t u; float f; } v; v.u = ((uint32_t)b) << 16;
    return v.f;
}
__device__ __forceinline__ float bits2f(u32 u) {
    union { uint32_t u; float f; } v; v.u = u;
    return v.f;
}
__device__ __forceinline__ void split2(float x, u16& h, u16& l) {
    h = f2bf(x); l = f2bf(x - bf2f(h));
}
__device__ __forceinline__ float sthr(float x) {
    float ax = fabsf(x) - LMDA;
    return ax > 0.0f ? copysignf(ax, x) : 0.0f;
}

// async 16B global -> LDS (HW writes lane l at ldsbase + l*16)
__device__ __forceinline__ void gload16(const u16* g, u16* l) {
    __builtin_amdgcn_global_load_lds(
        (const __attribute__((address_space(1))) unsigned int*)(const void*)g,
        (__attribute__((address_space(3))) unsigned int*)(void*)l, 16, 0, 0);
}

// ---------------------------------------------------------------------------
// ITERATION KERNEL (r12 geometry + T4 counted-vmcnt depth-2 pipeline).
//   R@W = 0.8*R + Rh@Wo   (Wo = -0.2*offdiag(U@U^T), single bf16, 2 MB)
// Tile 64m x 128n, grid 256 (32tr x 8tc), 512 thr = 8 waves (2mr x 4nc),
// wavetile 32x32 = 2x2 frags of 16x16x32, BK=64 -> 16 k-steps.
// LDS: 3 x 24KB fragment-ordered 1KB chunks (lane*16B = linear
// global_load_lds dest, conflict-free ds_read_b128), 3 loads/thread/step.
// Pipeline (never drain in loop): step s top = vmcnt(3) [stage(s) done,
// stage(s+1)'s 3 loads in flight] -> barrier -> issue stage(s+2) into
// buf (s+2)%3 [overwrites buf (s-1)%3, whose reads finished before the
// step-s barrier] -> ds_read buf s%3 + 8 MFMA.
// Epilogue: R' = split(st(acc + 0.8*(Rh+Rl) + unpack(Cp))), Cp = packed
// bf16-pair Csc (4 MB instead of 8 MB fp32).
// ---------------------------------------------------------------------------
__global__ __launch_bounds__(512, 2)
void pc_step(const u16* __restrict__ Rh, const u16* __restrict__ Rl,
             const u16* __restrict__ Woh, const u32* __restrict__ Cp,
             u16* __restrict__ Nh, u16* __restrict__ Nl)
{
    __shared__ __align__(16) u16 S[3][24 * 512];   // 3 x 24 KiB

    // XCD-aware bijective swizzle (256 % 8 == 0)
    const int fid = blockIdx.x;
    const int sid = (fid & 7) * 32 + (fid >> 3);
    const int tr = sid >> 3;              // 0..31
    const int tc = sid & 7;               // 0..7
    const int row0 = tr << 6;             // R rows [row0, +64)
    const int col0 = tc << 7;             // n cols [col0, +128)

    const int tid  = threadIdx.x;
    const int lane = tid & 63;
    const int w    = tid >> 6;            // 0..7
    const int mr   = w >> 2;              // 0..1 (m-half)
    const int nc   = w & 3;               // 0..3 (n-quarter)
    const int l15  = lane & 15;
    const int lg   = lane >> 4;           // 0..3
    const int l8   = lane << 3;           // u16 offset of lane's 16B

    // ---- staging: 24 chunks of 1KB per step (8 Rh + 16 Wo), 3 per thread --
    // A chunk c in [0,8):  kh=(c>>2)&1, g=c&3 : Rh rows row0+g*16
    // B chunk c in [8,24): cb=c-8, kh=cb>>3, g=cb&7 : Woh rows col0+g*16
    // lane l <- M[base_row + (l&15)][k0 + kh*32 + (l>>4)*8 .. +8)
    const u16* gsrc[3];
    int loff[3];
    #pragma unroll
    for (int t = 0; t < 3; ++t) {
        const int c = w * 3 + t;
        const u16* base;
        int r, kh;
        if (c < 8) {
            kh = (c >> 2) & 1;
            base = Rh;
            r = row0 + ((c & 3) << 4) + l15;
        } else {
            const int cb = c - 8;
            kh = cb >> 3;
            base = Woh;
            r = col0 + ((cb & 7) << 4) + l15;
        }
        gsrc[t] = base + ((size_t)r << 10) + (kh << 5) + (lg << 3);
        loff[t] = (c << 9) + l8;
    }
    auto stage = [&](int b, int k) {
        #pragma unroll
        for (int t = 0; t < 3; ++t)
            gload16(gsrc[t] + k, &S[b][loff[t]]);
    };

    f32x4 acc[2][2] = {};   // [mf][nf]

    stage(0, 0);
    stage(1, 64);

    for (int s = 0; s < 16; ++s) {
        if (s < 15) asm volatile("s_waitcnt vmcnt(3)" ::: "memory");
        else        asm volatile("s_waitcnt vmcnt(0)" ::: "memory");
        __builtin_amdgcn_s_barrier();
        asm volatile("" ::: "memory");
        if (s + 2 < 16) {
            int nb = s + 2; nb -= (nb >= 3) ? 3 : 0; nb -= (nb >= 3) ? 3 : 0;
            // (s+2)%3 without div: s in [0,13] -> s+2 in [2,15]
            nb = (s + 2) % 3;
            stage(nb, (s + 2) << 6);
        }

        const u16* Sb = S[s % 3];
        bf16x8 rh[2][2], wo[2][2];
        #pragma unroll
        for (int kh = 0; kh < 2; ++kh) {
            #pragma unroll
            for (int mf = 0; mf < 2; ++mf) {
                const int g = (mr << 1) + mf;
                rh[mf][kh] = *(const bf16x8*)&Sb[(((kh << 2) + g) << 9) + l8];
            }
            #pragma unroll
            for (int nf = 0; nf < 2; ++nf) {
                const int g = (nc << 1) + nf;
                wo[nf][kh] = *(const bf16x8*)&Sb[((8 + (kh << 3) + g) << 9) + l8];
            }
        }
        #pragma unroll
        for (int kh = 0; kh < 2; ++kh)
            #pragma unroll
            for (int mf = 0; mf < 2; ++mf)
                #pragma unroll
                for (int nf = 0; nf < 2; ++nf)
                    acc[mf][nf] = __builtin_amdgcn_mfma_f32_16x16x32_bf16(
                        wo[nf][kh], rh[mf][kh], acc[mf][nf], 0, 0, 0);
        asm volatile("" ::: "memory");
    }

    // ---- fused epilogue (D layout: col=m-local, row=n-local) ----
    #pragma unroll
    for (int mf = 0; mf < 2; ++mf) {
        #pragma unroll
        for (int nf = 0; nf < 2; ++nf) {
            const int m  = row0 + (mr << 5) + (mf << 4) + l15;
            const int n0 = col0 + (nc << 5) + (nf << 4) + (lg << 2);
            const size_t idx = ((size_t)m << 10) + n0;
            const u16x4 rh4 = *(const u16x4*)&Rh[idx];
            const u16x4 rl4 = *(const u16x4*)&Rl[idx];
            const u32x4 cp4 = *(const u32x4*)&Cp[idx];
            u16x4 hv, lv;
            #pragma unroll
            for (int e = 0; e < 4; ++e) {
                const float cs = bits2f(cp4[e] & 0xFFFF0000u) + bits2f(cp4[e] << 16);
                float r = bf2f(rh4[e]) + bf2f(rl4[e]);
                float x = acc[mf][nf][e] + 0.8f * r + cs;
                u16 hh, ll; split2(sthr(x), hh, ll);
                hv[e] = hh; lv[e] = ll;
            }
            *(u16x4*)&Nh[idx] = hv;
            *(u16x4*)&Nl[idx] = lv;
        }
    }
}

// ---------------------------------------------------------------------------
// FINAL-OUT KERNEL (r12's gemm_one<2,1>, passing): acc = (Rh+Rl)@Ut, fp32 out.
// ---------------------------------------------------------------------------
__global__ __launch_bounds__(512, 2)
void gemm_fin(const u16* __restrict__ Rh, const u16* __restrict__ Rl,
              const u16* __restrict__ Bm, float* __restrict__ OutF)
{
    constexpr int NCH = 32;
    __shared__ __align__(16) u16 S[2][NCH * 512];

    const int fid = blockIdx.x;
    const int sid = (fid & 7) * 32 + (fid >> 3);
    const int tr = sid >> 3;
    const int tc = sid & 7;
    const int row0 = tr << 6;
    const int col0 = tc << 7;

    const int tid  = threadIdx.x;
    const int lane = tid & 63;
    const int w    = tid >> 6;
    const int mr   = w >> 2;
    const int nc   = w & 3;
    const int l15  = lane & 15;
    const int lg   = lane >> 4;
    const int l8   = lane << 3;

    const u16* gsrc[4];
    int loff[4];
    #pragma unroll
    for (int t = 0; t < 4; ++t) {
        const int c = (w << 2) + t;
        const u16* base;
        int r, kh;
        if (c < 16) {
            const int h = c >> 3;
            kh = (c >> 2) & 1;
            base = h ? Rl : Rh;
            r = row0 + ((c & 3) << 4) + l15;
        } else {
            const int cb = c - 16;
            kh = cb >> 3;
            base = Bm;
            r = col0 + ((cb & 7) << 4) + l15;
        }
        gsrc[t] = base + ((size_t)r << 10) + (kh << 5) + (lg << 3);
        loff[t] = (c << 9) + l8;
    }
    auto stage = [&](int b, int k) {
        #pragma unroll
        for (int t = 0; t < 4; ++t)
            gload16(gsrc[t] + k, &S[b][loff[t]]);
    };

    f32x4 acc[2][2] = {};

    stage(0, 0);

    for (int s = 0; s < 16; ++s) {
        asm volatile("s_waitcnt vmcnt(0)" ::: "memory");
        __builtin_amdgcn_s_barrier();
        asm volatile("" ::: "memory");
        if (s < 15) stage((s + 1) & 1, (s + 1) << 6);

        const u16* Sb = S[s & 1];
        bf16x8 rh[2][2], rl[2][2], wo[2][2];
        #pragma unroll
        for (int kh = 0; kh < 2; ++kh) {
            #pragma unroll
            for (int mf = 0; mf < 2; ++mf) {
                const int g = (mr << 1) + mf;
                rh[mf][kh] = *(const bf16x8*)&Sb[(((kh << 2) + g) << 9) + l8];
                rl[mf][kh] = *(const bf16x8*)&Sb[((8 + (kh << 2) + g) << 9) + l8];
            }
            #pragma unroll
            for (int nf = 0; nf < 2; ++nf) {
                const int g = (nc << 1) + nf;
                wo[nf][kh] = *(const bf16x8*)&Sb[((16 + (kh << 3) + g) << 9) + l8];
            }
        }
        #pragma unroll
        for (int kh = 0; kh < 2; ++kh)
            #pragma unroll
            for (int mf = 0; mf < 2; ++mf)
                #pragma unroll
                for (int nf = 0; nf < 2; ++nf) {
                    acc[mf][nf] = __builtin_amdgcn_mfma_f32_16x16x32_bf16(
                        wo[nf][kh], rh[mf][kh], acc[mf][nf], 0, 0, 0);
                    acc[mf][nf] = __builtin_amdgcn_mfma_f32_16x16x32_bf16(
                        wo[nf][kh], rl[mf][kh], acc[mf][nf], 0, 0, 0);
                }
        asm volatile("" ::: "memory");
    }

    #pragma unroll
    for (int mf = 0; mf < 2; ++mf)
        #pragma unroll
        for (int nf = 0; nf < 2; ++nf) {
            const int m  = row0 + (mr << 5) + (mf << 4) + l15;
            const int n0 = col0 + (nc << 5) + (nf << 4) + (lg << 2);
            *(f32x4*)&OutF[((size_t)m << 10) + n0] = acc[mf][nf];
        }
}

// ---------------------------------------------------------------------------
// PROLOGUE GEMM (round-5 machinery, passing): fused-3 split-bf16 NT GEMM.
// EPI 1: Cp = pack(split(0.2*acc)) ; R = split(st(0.2*acc))   (Csc and R1)
// EPI 4: OutH = f2bf(diag? 0 : -0.2*acc)                      (Woh)
// ---------------------------------------------------------------------------
template<int EPI>
__global__ __launch_bounds__(512, 2)
void gemm_ista(const u16* __restrict__ Ah, const u16* __restrict__ Al,
               const u16* __restrict__ Bh, const u16* __restrict__ Bl,
               int Nt,
               u32* __restrict__ OutP,
               u16* __restrict__ OutH, u16* __restrict__ OutL)
{
    __shared__ __align__(16) u16 S[3][48 * 512];   // 144 KiB

    const int nwg = gridDim.x;
    const int fid = blockIdx.x;
    const int sid = (fid & 7) * (nwg >> 3) + (fid >> 3);
    const int row0 = (sid / Nt) << 7;
    const int col0 = (sid % Nt) << 6;

    const int tid  = threadIdx.x;
    const int lane = tid & 63;
    const int w    = tid >> 6;
    const int mr = w >> 2, nc = (w >> 1) & 1, ks = w & 1;

    const u16* gb[6];
    int cf[6];
    #pragma unroll
    for (int t = 0; t < 6; ++t) {
        const int c = w * 6 + t;
        const u16* base; int r; int kss;
        if (c < 32) {
            const int h = (c >> 4) & 1; kss = (c >> 3) & 1;
            base = h ? Al : Ah;
            r = row0 + ((c & 7) << 4) + (lane & 15);
        } else {
            const int cb = c - 32;
            const int h = (cb >> 3) & 1; kss = (cb >> 2) & 1;
            base = h ? Bl : Bh;
            r = col0 + ((cb & 3) << 4) + (lane & 15);
        }
        gb[t] = base + ((size_t)r << 10) + (kss << 5) + ((lane >> 4) << 3);
        cf[t] = c << 9;
    }
    auto stage = [&](int b, int koff) {
        #pragma unroll
        for (int t = 0; t < 6; ++t)
            gload16(gb[t] + koff, &S[b][cf[t]]);
    };

    f32x4 acc[4][2] = {};

    stage(0, 0);
    stage(1, 64);

    #pragma unroll
    for (int s = 0; s < 16; ++s) {
        if (s <= 14) asm volatile("s_waitcnt vmcnt(6)" ::: "memory");
        else         asm volatile("s_waitcnt vmcnt(0)" ::: "memory");
        __builtin_amdgcn_s_barrier();
        asm volatile("" ::: "memory");
        if (s + 2 < 16) stage((s + 2) % 3, (s + 2) << 6);

        const u16* Sb = S[s % 3];
        const int ab = (ks << 3) + (mr << 2);
        const int bb = 32 + (ks << 2) + (nc << 1);
        bf16x8 ah[4], al[4], bh[2], bl[2];
        #pragma unroll
        for (int i = 0; i < 4; ++i) {
            ah[i] = *(const bf16x8*)&Sb[(ab + i)      * 512 + (lane << 3)];
            al[i] = *(const bf16x8*)&Sb[(ab + 16 + i) * 512 + (lane << 3)];
        }
        #pragma unroll
        for (int j = 0; j < 2; ++j) {
            bh[j] = *(const bf16x8*)&Sb[(bb + j)     * 512 + (lane << 3)];
            bl[j] = *(const bf16x8*)&Sb[(bb + 8 + j) * 512 + (lane << 3)];
        }
        #pragma unroll
        for (int i = 0; i < 4; ++i)
            #pragma unroll
            for (int j = 0; j < 2; ++j)
                acc[i][j] = __builtin_amdgcn_mfma_f32_16x16x32_bf16(ah[i], bh[j], acc[i][j], 0, 0, 0);
        #pragma unroll
        for (int i = 0; i < 4; ++i)
            #pragma unroll
            for (int j = 0; j < 2; ++j)
                acc[i][j] = __builtin_amdgcn_mfma_f32_16x16x32_bf16(al[i], bh[j], acc[i][j], 0, 0, 0);
        #pragma unroll
        for (int i = 0; i < 4; ++i)
            #pragma unroll
            for (int j = 0; j < 2; ++j)
                acc[i][j] = __builtin_amdgcn_mfma_f32_16x16x32_bf16(ah[i], bl[j], acc[i][j], 0, 0, 0);
        asm volatile("" ::: "memory");
    }

    __syncthreads();
    f32x4* red = (f32x4*)&S[0][0];
    const int wquad = (mr << 1) + nc;
    #pragma unroll
    for (int ih = 0; ih < 2; ++ih) {
        #pragma unroll
        for (int j = 0; j < 2; ++j) {
            const int isrc = ks ? ih : (2 + ih);
            const int slot = ((((wquad << 1) | ks) << 2) | (ih << 1) | j);
            red[slot * 64 + lane] = acc[isrc][j];
        }
    }
    __syncthreads();

    const int gr0 = row0 + (mr << 6) + ((lane >> 4) << 2);
    const int gc  = col0 + (nc << 5) + (lane & 15);
    #pragma unroll
    for (int ih = 0; ih < 2; ++ih) {
        #pragma unroll
        for (int j = 0; j < 2; ++j) {
            const int i    = ks ? (2 + ih) : ih;
            const int slot = ((((wquad << 1) | (ks ^ 1)) << 2) | (ih << 1) | j);
            f32x4 sum = acc[i][j] + red[slot * 64 + lane];
            #pragma unroll
            for (int e = 0; e < 4; ++e) {
                const int grow = gr0 + (i << 4) + e;
                const int gcol = gc + (j << 4);
                const size_t idx = ((size_t)grow << 10) + gcol;
                const float p = sum[e];
                if (EPI == 1) {
                    float f = 0.2f * p;
                    u16 ch, cl; split2(f, ch, cl);
                    OutP[idx] = (((u32)ch) << 16) | (u32)cl;
                    u16 h, l; split2(sthr(f), h, l);
                    OutH[idx] = h; OutL[idx] = l;
                } else {   // EPI 4: Woh = bf16(-0.2*offdiag)
                    float x = (grow == gcol) ? 0.0f : -0.2f * p;
                    OutH[idx] = f2bf(x);
                }
            }
        }
    }
}

// fp32 -> (hi, lo) bf16 pair, elementwise
__global__ void k_split(const float* __restrict__ in, u16* __restrict__ hi,
                        u16* __restrict__ lo, int n)
{
    int i = blockIdx.x * 256 + threadIdx.x;
    if (i < n) { u16 h, l; split2(in[i], h, l); hi[i] = h; lo[i] = l; }
}

// Ut[j][k] = U[k][j] as bf16 pair
__global__ __launch_bounds__(256)
void k_transpose_split(const float* __restrict__ in, u16* __restrict__ hi,
                       u16* __restrict__ lo)
{
    __shared__ float t[32][33];
    const int bx = blockIdx.x, by = blockIdx.y;
    const int lx = threadIdx.x & 31, ly = threadIdx.x >> 5;
    #pragma unroll
    for (int rr = 0; rr < 4; ++rr) {
        int r = ly * 4 + rr;
        t[r][lx] = in[(size_t)(by * 32 + r) * 1024 + bx * 32 + lx];
    }
    __syncthreads();
    #pragma unroll
    for (int rr = 0; rr < 4; ++rr) {
        int r = ly * 4 + rr;
        u16 h, l; split2(t[lx][r], h, l);
        size_t idx = (size_t)(bx * 32 + r) * 1024 + by * 32 + lx;
        hi[idx] = h; lo[idx] = l;
    }
}

extern "C" void kernel_launch(void* const* d_in, const int* in_sizes, int n_in,
                              void* d_out, int out_size, void* d_ws, size_t ws_size,
                              hipStream_t stream) {
    const float* img = (const float*)d_in[0];   // (2048, 1024) fp32
    const float* U   = (const float*)d_in[1];   // (1024, 1024) fp32
    float* out = (float*)d_out;                 // (2048, 1024) fp32

    char* ws = (char*)d_ws;
    auto MB = [](size_t m) { return m << 20; };
    u16*   Uh  = (u16*)(ws + MB(0));
    u16*   Ul  = (u16*)(ws + MB(2));
    u16*   Uth = (u16*)(ws + MB(4));
    u16*   Utl = (u16*)(ws + MB(6));
    u16*   Woh = (u16*)(ws + MB(8));             // 2 MB single-bf16 offdiag W
    u32*   Cp  = (u32*)(ws + MB(12));            // 4 MB packed bf16-pair Csc
    u16*   Rah = (u16*)(ws + MB(20));
    u16*   Ral = (u16*)(ws + MB(24));
    u16*   Rbh = (u16*)(ws + MB(28));
    u16*   Rbl = (u16*)(ws + MB(32));            // ends at 36 MB
    u16*   Ih  = Rbh;   // img split lives only until Csc is built
    u16*   Il  = Rbl;

    // ---- prologue ----
    k_split<<<4096, 256, 0, stream>>>(U, Uh, Ul, 1024 * 1024);
    k_split<<<8192, 256, 0, stream>>>(img, Ih, Il, 2048 * 1024);
    k_transpose_split<<<dim3(32, 32), 256, 0, stream>>>(U, Uth, Utl);

    // Woh = bf16(-0.2 * offdiag(U @ U^T))
    gemm_ista<4><<<128, 512, 0, stream>>>(Uh, Ul, Uh, Ul, 16,
                                          nullptr, Woh, nullptr);
    // Cp = pack(0.2 * img @ U^T) ; R1 = st(Csc)
    gemm_ista<1><<<256, 512, 0, stream>>>(Ih, Il, Uh, Ul, 16,
                                          Cp, Rah, Ral);

    // ---- iterations 2..150: R <- st(0.8R + Rh@Wo + Csc), 1 kernel/iter ----
    u16 *ch = Rah, *cl = Ral, *nh = Rbh, *nl = Rbl;
    for (int it = 0; it < 149; ++it) {
        pc_step<<<256, 512, 0, stream>>>(ch, cl, Woh, Cp, nh, nl);
        u16* t;
        t = ch; ch = nh; nh = t;
        t = cl; cl = nl; nl = t;
    }

    // ---- out = R @ U (2-product against Ut, one-shot) ----
    gemm_fin<<<256, 512, 0, stream>>>(ch, cl, Uth, out);
}